// Round 15
// baseline (839.984 us; speedup 1.0000x reference)
//
#include <hip/hip_runtime.h>

// Problem constants (from reference): B=256, T=2048, I=12, H=64
constexpr int Bn = 256;
constexpr int Tn = 2048;
constexpr int In = 12;
constexpr int Hn = 64;
constexpr int TCH = 512;     // steps per staged x quarter (padded to 16 floats)
constexpr int CHUNK = 16;    // fc-flush granularity == hist depth

constexpr float LOG2E = 1.44269504088896340736f;

__device__ __forceinline__ float frcp(float v) { return __builtin_amdgcn_rcpf(v); }

// quad_perm DPP: cross-lane move within each group of 4 lanes, pure VALU.
template <int CTRL>
__device__ __forceinline__ float dppq(float v) {
    int i = __float_as_int(v);
    i = __builtin_amdgcn_mov_dpp(i, CTRL, 0xF, 0xF, false);
    return __int_as_float(i);
}
// readlane: SGPR broadcast of lane L's value (ignores exec).
__device__ __forceinline__ float rdl(float v, int l) {
    return __int_as_float(__builtin_amdgcn_readlane(__float_as_int(v), l));
}

// Round-15 mapping: 512 threads = 8 waves, 2 per SIMD (latency overlap).
//   PARTIAL: wave w owns K-slice h[8w..8w+8) + x cols {2w,2w+1} (w<6).
//     Lane l computes partial dots for rows R_m = 64m + l (m=0..3 = gate).
//     40 FMA/lane. Store at pbuf[w][72*m + l] (index = 72*gate + jown):
//     write banks (8m+l)%32 -> 2 lanes/bank (free);
//     reduce-read banks (8g+8w+i8)%32 -> all 32 banks (conflict-free).
//   REDUCE (dup on both 32-lane halves): lh=lane&31, g=lh&3, i8=lh>>2,
//     jown = 8w+i8, ro = 64g+jown. Sum 8 wave-partials + bias, activate,
//     quad-DPP i/f/g/o, quad-redundant c/h, 8 readlanes -> next-step h.
extern "C" __global__ void __launch_bounds__(512, 1)
lstm_fused_kernel(const float* __restrict__ x,
                  const float* __restrict__ w_ih,
                  const float* __restrict__ w_hh,
                  const float* __restrict__ b_ih,
                  const float* __restrict__ b_hh,
                  const float* __restrict__ fc_w,
                  const float* __restrict__ fc_b,
                  float* __restrict__ out)
{
    __shared__ __align__(16) float xbuf[TCH * 16];        // 32 KiB (x quarter)
    __shared__ __align__(16) float pbuf[2][8][288];       // 18 KiB partials
    __shared__ __align__(16) float hist[CHUNK][Hn];       // 4 KiB (fc only)

    const int tid  = threadIdx.x;
    const int lane = tid & 63;
    const int w    = tid >> 6;          // wave id 0..7
    const int lh   = lane & 31;
    const int g    = lh & 3;            // gate type 0:i 1:f 2:g 3:o
    const int i8   = lh >> 2;           // 0..7
    const int jown = 8 * w + i8;        // h index owned in reduce phase
    const int ro   = 64 * g + jown;     // reduce-phase row
    const int b    = blockIdx.x;

    const float4* xsrc4 = (const float4*)(x + (size_t)b * Tn * In);

    // ---- zero the x padding columns (i = 12..15) once ----
    {
        float4 z; z.x = z.y = z.z = z.w = 0.0f;
        ((float4*)xbuf)[tid * 4 + 3] = z;               // row tid, pad slot
    }

    // ---- per-lane weight slices: rows 64m+lane, K-slice [8w..8w+8) ----
    float whh_s[4][8];
    #pragma unroll
    for (int mm = 0; mm < 4; ++mm) {
        const float4* src = (const float4*)(w_hh + (64 * mm + lane) * Hn + 8 * w);
        float4 v0 = src[0], v1 = src[1];
        whh_s[mm][0]=v0.x; whh_s[mm][1]=v0.y; whh_s[mm][2]=v0.z; whh_s[mm][3]=v0.w;
        whh_s[mm][4]=v1.x; whh_s[mm][5]=v1.y; whh_s[mm][6]=v1.z; whh_s[mm][7]=v1.w;
    }
    #pragma unroll
    for (int mm = 0; mm < 4; ++mm)
        #pragma unroll
        for (int k = 0; k < 8; k += 4)
            asm volatile("" : "+v"(whh_s[mm][k+0]), "+v"(whh_s[mm][k+1]),
                              "+v"(whh_s[mm][k+2]), "+v"(whh_s[mm][k+3]));

    float wih_s[4][2];
    if (w < 6) {
        #pragma unroll
        for (int mm = 0; mm < 4; ++mm) {
            float2 v = *(const float2*)(w_ih + (64 * mm + lane) * In + 2 * w);
            wih_s[mm][0] = v.x; wih_s[mm][1] = v.y;
        }
    } else {
        #pragma unroll
        for (int mm = 0; mm < 4; ++mm) { wih_s[mm][0] = 0.0f; wih_s[mm][1] = 0.0f; }
    }
    #pragma unroll
    for (int mm = 0; mm < 4; ++mm)
        asm volatile("" : "+v"(wih_s[mm][0]), "+v"(wih_s[mm][1]));

    const float bias = b_ih[ro] + b_hh[ro];
    // act = scl * sigma(scl*a) + soff:  g!=2 -> sigma(a);  g==2 -> tanh(a)
    const float scl  = (g == 2) ? 2.0f : 1.0f;
    const float soff = (g == 2) ? -1.0f : 0.0f;
    const float me   = (g == 2) ? (-2.0f * LOG2E) : (-LOG2E);
    // fc flush constants (tid < 256 active)
    const int   fq   = tid & 15;
    const int   fs   = (tid >> 4) & 15;
    const float4 fw4 = *(const float4*)(fc_w + 4 * fq);
    const float fcb  = fc_b[0];

    float h_own = 0.0f;                 // h[jown] (quad-redundant, both halves)
    float c     = 0.0f;                 // cell state for jown

    float* outb = out + (size_t)b * Tn;

    for (int ci = 0; ci < Tn / CHUNK; ++ci) {
        const int T0 = ci * CHUNK;

        // ---- stage x quarter (old quarter reads all pre-barrier) ----
        if ((T0 & (TCH - 1)) == 0) {
            const int qtr = T0 >> 9;
            #pragma unroll
            for (int k = 0; k < 3; ++k) {
                int li  = tid + k * 512;              // 0..1535 (local float4)
                int t_l = li / 3;                     // local step
                int i4  = li % 3;                     // float4 slot within row
                ((float4*)xbuf)[t_l * 4 + i4] = xsrc4[qtr * 1536 + li];
            }
            __syncthreads();
        }

        #pragma unroll
        for (int s = 0; s < CHUNK; ++s) {
            const int tl = (T0 + s) & (TCH - 1);

            // ---- x read early (uniform per wave -> broadcast) ----
            float2 xv;
            xv.x = 0.0f; xv.y = 0.0f;
            if (w < 6) xv = *(const float2*)(xbuf + tl * 16 + 2 * w);

            // ---- SGPR h-broadcast (quad lane 4k holds h[8w+k]) ----
            float hs0 = rdl(h_own,  0), hs1 = rdl(h_own,  4);
            float hs2 = rdl(h_own,  8), hs3 = rdl(h_own, 12);
            float hs4 = rdl(h_own, 16), hs5 = rdl(h_own, 20);
            float hs6 = rdl(h_own, 24), hs7 = rdl(h_own, 28);

            // ---- partial phase: rows 64m+lane over wave's K-slice ----
            float p0 = hs0 * whh_s[0][0], p1 = hs0 * whh_s[1][0];
            float p2 = hs0 * whh_s[2][0], p3 = hs0 * whh_s[3][0];
            #define HFMA(K, HS) \
                p0 = fmaf(HS, whh_s[0][K], p0);  p1 = fmaf(HS, whh_s[1][K], p1); \
                p2 = fmaf(HS, whh_s[2][K], p2);  p3 = fmaf(HS, whh_s[3][K], p3);
            HFMA(1, hs1) HFMA(2, hs2) HFMA(3, hs3)
            HFMA(4, hs4) HFMA(5, hs5) HFMA(6, hs6) HFMA(7, hs7)
            #undef HFMA
            if (w < 6) {
                p0 = fmaf(xv.x, wih_s[0][0], p0);  p1 = fmaf(xv.x, wih_s[1][0], p1);
                p2 = fmaf(xv.x, wih_s[2][0], p2);  p3 = fmaf(xv.x, wih_s[3][0], p3);
                p0 = fmaf(xv.y, wih_s[0][1], p0);  p1 = fmaf(xv.y, wih_s[1][1], p1);
                p2 = fmaf(xv.y, wih_s[2][1], p2);  p3 = fmaf(xv.y, wih_s[3][1], p3);
            }

            // ---- store partials: index 72*gate + jown (bank-spread) ----
            {
                float* pw = &pbuf[s & 1][w][0];
                pw[lane]       = p0;
                pw[72 + lane]  = p1;
                pw[144 + lane] = p2;
                pw[216 + lane] = p3;
            }
            __syncthreads();               // the ONE barrier per step

            // ---- reduce phase (dup both halves): row ro ----
            {
                const float* pr = &pbuf[s & 1][0][0];
                const int rb = 72 * g + jown;
                float q0 = pr[rb],            q1 = pr[288  + rb];
                float q2 = pr[576 + rb],      q3 = pr[864  + rb];
                float q4 = pr[1152 + rb],     q5 = pr[1440 + rb];
                float q6 = pr[1728 + rb],     q7 = pr[2016 + rb];
                float a = (((q0 + q1) + (q2 + q3)) + ((q4 + q5) + (q6 + q7))) + bias;

                float e   = exp2f(me * a);
                float act = fmaf(scl, frcp(1.0f + e), soff);

                float iv = dppq<0x00>(act);
                float fv = dppq<0x55>(act);
                float gv = dppq<0xAA>(act);
                float ov = dppq<0xFF>(act);

                c = fmaf(fv, c, iv * gv);
                float e2 = exp2f(-2.0f * LOG2E * c);
                h_own = ov * fmaf(2.0f, frcp(1.0f + e2), -1.0f);

                if (g == 0 && lane < 32) hist[s][jown] = h_own;  // fc history
            }
        }

        // ---- fc flush: lower 256 threads reduce hist[16][64] -> 16 outputs ----
        __syncthreads();
        if (tid < 256) {
            const float4 hv = *(const float4*)(&hist[fs][4 * fq]);
            float pp = hv.x * fw4.x + hv.y * fw4.y + hv.z * fw4.z + hv.w * fw4.w;
            #pragma unroll
            for (int off = 8; off; off >>= 1)
                pp += __shfl_xor(pp, off, 16);
            if (fq == 0) outb[T0 + fs] = pp + fcb;
        }
    }
}

extern "C" void kernel_launch(void* const* d_in, const int* in_sizes, int n_in,
                              void* d_out, int out_size, void* d_ws, size_t ws_size,
                              hipStream_t stream) {
    const float* x    = (const float*)d_in[0];
    const float* w_ih = (const float*)d_in[1];
    const float* w_hh = (const float*)d_in[2];
    const float* b_ih = (const float*)d_in[3];
    const float* b_hh = (const float*)d_in[4];
    const float* fc_w = (const float*)d_in[5];
    const float* fc_b = (const float*)d_in[6];
    float* out = (float*)d_out;

    lstm_fused_kernel<<<Bn, 512, 0, stream>>>(x, w_ih, w_hh, b_ih, b_hh,
                                              fc_w, fc_b, out);
}